// Round 1
// 1484.709 us; speedup vs baseline: 1.2167x; 1.2167x over previous
//
#include <hip/hip_runtime.h>
#include <cstdint>
#include <cstddef>

#define NB 8
#define SL 1024
#define ED 1024
#define NH 16
#define DKH 64

typedef __attribute__((ext_vector_type(4))) float f32x4;
typedef __attribute__((ext_vector_type(8))) short short8;

// LDS row stride in bf16 elements: 32 payload + 8 pad (80 B = 16B-aligned, breaks pow2 bank stride)
#define LDSW 40

__device__ __forceinline__ unsigned short bf16_rn(float x) {
    unsigned int u = __float_as_uint(x);
    u += 0x7FFFu + ((u >> 16) & 1u);
    return (unsigned short)(u >> 16);
}
__device__ __forceinline__ float bf16_f(unsigned short h) {
    return __uint_as_float(((unsigned int)h) << 16);
}
__device__ __forceinline__ void split2(float x, unsigned short& hi, unsigned short& lo) {
    unsigned short h = bf16_rn(x);
    hi = h;
    lo = bf16_rn(x - bf16_f(h));
}

// 64x64 tile GEMM core, BK=32, 256 threads (4 waves), 16x16x32 bf16 MFMA, 3-term hi/lo split.
// A: APRE ? pre-split hi/lo ushort row-major [m][k] : fp32 row-major (split in-kernel, once/element).
// B: ALWAYS pre-split hi/lo ushort in [n][k] row-major layout (ldb = row stride in elements).
// Verified fragment layouts preserved from previous version:
//   A[m=l16][k=quad*8+j], B[n=l16(+16j)][k=quad*8+j], C col=l16, row=quad*4+r.
template<bool APRE>
__device__ __forceinline__ void gemm_core2(
    const float* __restrict__ Af,
    const unsigned short* __restrict__ Ahg, const unsigned short* __restrict__ Alg,
    int lda,
    const unsigned short* __restrict__ Bhg, const unsigned short* __restrict__ Blg,
    int ldb,
    int Kd, int m0, int n0, f32x4 acc[4])
{
    __shared__ unsigned short Ahi[64 * LDSW];
    __shared__ unsigned short Alo[64 * LDSW];
    __shared__ unsigned short Bhi[64 * LDSW];
    __shared__ unsigned short Blo[64 * LDSW];

    const int tid  = threadIdx.x;
    const int wave = tid >> 6;
    const int lane = tid & 63;
    const int quad = lane >> 4;
    const int l16  = lane & 15;
    const int r    = tid >> 2;        // 0..63 : staged row
    const int cc   = (tid & 3) * 8;   // 0,8,16,24 : k-offset (shorts)

#pragma unroll
    for (int j = 0; j < 4; j++) acc[j] = (f32x4)(0.0f);

    for (int k0 = 0; k0 < Kd; k0 += 32) {
        __syncthreads();
        // ---- stage A: one 16B vector copy per plane (or split-once from fp32) ----
        if constexpr (APRE) {
            const size_t off = (size_t)(m0 + r) * lda + k0 + cc;
            *(short8*)&Ahi[r * LDSW + cc] = *(const short8*)(Ahg + off);
            *(short8*)&Alo[r * LDSW + cc] = *(const short8*)(Alg + off);
        } else {
            const float* p = Af + (size_t)(m0 + r) * lda + k0 + cc;
            const float4 v0 = *(const float4*)p;
            const float4 v1 = *(const float4*)(p + 4);
            short8 h8, l8;
            unsigned short h, l;
            split2(v0.x, h, l); h8[0] = (short)h; l8[0] = (short)l;
            split2(v0.y, h, l); h8[1] = (short)h; l8[1] = (short)l;
            split2(v0.z, h, l); h8[2] = (short)h; l8[2] = (short)l;
            split2(v0.w, h, l); h8[3] = (short)h; l8[3] = (short)l;
            split2(v1.x, h, l); h8[4] = (short)h; l8[4] = (short)l;
            split2(v1.y, h, l); h8[5] = (short)h; l8[5] = (short)l;
            split2(v1.z, h, l); h8[6] = (short)h; l8[6] = (short)l;
            split2(v1.w, h, l); h8[7] = (short)h; l8[7] = (short)l;
            *(short8*)&Ahi[r * LDSW + cc] = h8;
            *(short8*)&Alo[r * LDSW + cc] = l8;
        }
        // ---- stage B: always a 16B vector copy per plane ----
        {
            const size_t off = (size_t)(n0 + r) * ldb + k0 + cc;
            *(short8*)&Bhi[r * LDSW + cc] = *(const short8*)(Bhg + off);
            *(short8*)&Blo[r * LDSW + cc] = *(const short8*)(Blg + off);
        }
        __syncthreads();

        const short8 ah = *(const short8*)&Ahi[(wave * 16 + l16) * LDSW + quad * 8];
        const short8 al = *(const short8*)&Alo[(wave * 16 + l16) * LDSW + quad * 8];
#pragma unroll
        for (int j = 0; j < 4; j++) {
            const short8 bh = *(const short8*)&Bhi[(j * 16 + l16) * LDSW + quad * 8];
            const short8 bl = *(const short8*)&Blo[(j * 16 + l16) * LDSW + quad * 8];
            acc[j] = __builtin_amdgcn_mfma_f32_16x16x32_bf16(al, bh, acc[j], 0, 0, 0);
            acc[j] = __builtin_amdgcn_mfma_f32_16x16x32_bf16(ah, bl, acc[j], 0, 0, 0);
            acc[j] = __builtin_amdgcn_mfma_f32_16x16x32_bf16(ah, bh, acc[j], 0, 0, 0);
        }
    }
}

// ---- weight transpose + split: W (E_in x E_out, [k][n]) -> WT hi/lo [n][k] ----
__global__ __launch_bounds__(256)
void k_wsplitT(const float* __restrict__ W,
               unsigned short* __restrict__ Th, unsigned short* __restrict__ Tl)
{
    __shared__ float tile[64 * 65];
    const int n0 = blockIdx.x * 64;
    const int k0 = blockIdx.y * 64;
    const int tid = threadIdx.x;
    for (int i = tid; i < 64 * 64; i += 256) {
        const int rk = i >> 6, cn = i & 63;
        tile[rk * 65 + cn] = W[(size_t)(k0 + rk) * ED + n0 + cn];
    }
    __syncthreads();
    for (int i = tid; i < 64 * 64; i += 256) {
        const int rn = i >> 6, ck = i & 63;
        unsigned short h, l;
        split2(tile[ck * 65 + rn], h, l);
        Th[(size_t)(n0 + rn) * ED + k0 + ck] = h;
        Tl[(size_t)(n0 + rn) * ED + k0 + ck] = l;
    }
}

// ---- q/k projection: writes pre-split heads layout [n,h,s,d] hi/lo ----
__global__ __launch_bounds__(256)
void k_projQK(const float* __restrict__ X,
              const unsigned short* __restrict__ Wh, const unsigned short* __restrict__ Wl,
              const float* __restrict__ bias,
              unsigned short* __restrict__ Oh, unsigned short* __restrict__ Ol)
{
    const int m0 = blockIdx.x * 64;
    const int n0 = blockIdx.y * 64;
    f32x4 acc[4];
    gemm_core2<false>(X, nullptr, nullptr, ED, Wh, Wl, ED, ED, m0, n0, acc);

    const int tid = threadIdx.x, wave = tid >> 6, lane = tid & 63;
    const int quad = lane >> 4, l16 = lane & 15;
#pragma unroll
    for (int j = 0; j < 4; j++) {
        const int col = n0 + j * 16 + l16;
        const int h = col >> 6, d = col & 63;
        const float b = bias[col];
#pragma unroll
        for (int rr = 0; rr < 4; rr++) {
            const int m = m0 + wave * 16 + quad * 4 + rr;
            const int n = m >> 10, s = m & 1023;
            const size_t idx = (((size_t)(n * NH + h)) * SL + s) * DKH + d;
            unsigned short hh, ll;
            split2(acc[j][rr] + b, hh, ll);
            Oh[idx] = hh;
            Ol[idx] = ll;
        }
    }
}

// ---- v projection: writes pre-split TRANSPOSED layout vT[ghead][d][s] hi/lo via LDS bounce ----
__global__ __launch_bounds__(256)
void k_projV(const float* __restrict__ X,
             const unsigned short* __restrict__ Wh, const unsigned short* __restrict__ Wl,
             const float* __restrict__ bias,
             unsigned short* __restrict__ Th, unsigned short* __restrict__ Tl)
{
    const int m0 = blockIdx.x * 64;
    const int n0 = blockIdx.y * 64;
    f32x4 acc[4];
    gemm_core2<false>(X, nullptr, nullptr, ED, Wh, Wl, ED, ED, m0, n0, acc);

    __shared__ unsigned int T[64 * 65];   // packed (hi | lo<<16), [s_local][d]
    const int tid = threadIdx.x, wave = tid >> 6, lane = tid & 63;
    const int quad = lane >> 4, l16 = lane & 15;
#pragma unroll
    for (int j = 0; j < 4; j++) {
        const int d = j * 16 + l16;
        const float b = bias[n0 + d];
#pragma unroll
        for (int rr = 0; rr < 4; rr++) {
            const int sl = wave * 16 + quad * 4 + rr;
            unsigned short hh, ll;
            split2(acc[j][rr] + b, hh, ll);
            T[sl * 65 + d] = (unsigned int)hh | ((unsigned int)ll << 16);
        }
    }
    __syncthreads();
    const int d  = tid >> 2;
    const int sc = (tid & 3) * 16;
    const int ghead = (m0 >> 10) * NH + (n0 >> 6);
    const int sbase = (m0 & 1023) + sc;
    short8 h0, h1, l0, l1;
#pragma unroll
    for (int i = 0; i < 8; i++) {
        const unsigned int u = T[(sc + i) * 65 + d];
        h0[i] = (short)(u & 0xFFFFu);
        l0[i] = (short)(u >> 16);
    }
#pragma unroll
    for (int i = 0; i < 8; i++) {
        const unsigned int u = T[(sc + 8 + i) * 65 + d];
        h1[i] = (short)(u & 0xFFFFu);
        l1[i] = (short)(u >> 16);
    }
    const size_t off = ((size_t)ghead * DKH + d) * SL + sbase;
    *(short8*)(Th + off)     = h0;
    *(short8*)(Th + off + 8) = h1;
    *(short8*)(Tl + off)     = l0;
    *(short8*)(Tl + off + 8) = l1;
}

// ---- logits: attn[head][s][t] = (qh @ kh^T)/8, masked; operands pre-split ----
__global__ __launch_bounds__(256)
void k_logits(const unsigned short* __restrict__ qh_h, const unsigned short* __restrict__ qh_l,
              const unsigned short* __restrict__ kh_h, const unsigned short* __restrict__ kh_l,
              const int* __restrict__ mask, float* __restrict__ attn)
{
    const int head = blockIdx.z;       // n*NH + h
    const int n = head >> 4;
    const int m0 = blockIdx.x * 64;
    const int n0 = blockIdx.y * 64;
    const size_t hb = (size_t)head * SL * DKH;
    f32x4 acc[4];
    gemm_core2<true>(nullptr, qh_h + hb, qh_l + hb, DKH,
                     kh_h + hb, kh_l + hb, DKH, DKH, m0, n0, acc);

    const int tid = threadIdx.x, wave = tid >> 6, lane = tid & 63;
    const int quad = lane >> 4, l16 = lane & 15;
    const float scale = 0.125f;  // 1/sqrt(64)
#pragma unroll
    for (int j = 0; j < 4; j++) {
        const int t = n0 + j * 16 + l16;
#pragma unroll
        for (int rr = 0; rr < 4; rr++) {
            const int s = m0 + wave * 16 + quad * 4 + rr;
            float vv = acc[j][rr] * scale;
            if (mask[((size_t)n * SL + s) * SL + t]) vv = -1e9f;
            attn[((size_t)head * SL + s) * SL + t] = vv;
        }
    }
}

// ---- row softmax in place: one wave per row, shuffle-only reductions ----
__global__ __launch_bounds__(256)
void k_softmax(float* __restrict__ attn)
{
    const int tid = threadIdx.x;
    const int wave = tid >> 6, lane = tid & 63;
    const size_t row = (size_t)blockIdx.x * 4 + wave;
    float* p = attn + row * SL;

    float4 v[4];
    float mx = -3.4e38f;
#pragma unroll
    for (int i = 0; i < 4; i++) {
        v[i] = *(const float4*)(p + lane * 4 + i * 256);
        mx = fmaxf(mx, fmaxf(fmaxf(v[i].x, v[i].y), fmaxf(v[i].z, v[i].w)));
    }
#pragma unroll
    for (int o = 32; o > 0; o >>= 1) mx = fmaxf(mx, __shfl_xor(mx, o));

    float sum = 0.0f;
#pragma unroll
    for (int i = 0; i < 4; i++) {
        v[i].x = __expf(v[i].x - mx);
        v[i].y = __expf(v[i].y - mx);
        v[i].z = __expf(v[i].z - mx);
        v[i].w = __expf(v[i].w - mx);
        sum += v[i].x + v[i].y + v[i].z + v[i].w;
    }
#pragma unroll
    for (int o = 32; o > 0; o >>= 1) sum += __shfl_xor(sum, o);

    const float inv = 1.0f / sum;
#pragma unroll
    for (int i = 0; i < 4; i++) {
        v[i].x *= inv; v[i].y *= inv; v[i].z *= inv; v[i].w *= inv;
        *(float4*)(p + lane * 4 + i * 256) = v[i];
    }
}

// ---- PV: oh[n][s][h*64+d] = P @ V, V pre-split transposed; writes oh pre-split ----
__global__ __launch_bounds__(256)
void k_pv(const float* __restrict__ attn,
          const unsigned short* __restrict__ vTh, const unsigned short* __restrict__ vTl,
          unsigned short* __restrict__ Oh, unsigned short* __restrict__ Ol)
{
    const int head = blockIdx.z;
    const int m0 = blockIdx.x * 64;
    const float* P = attn + (size_t)head * SL * SL;
    const unsigned short* Bh = vTh + (size_t)head * DKH * SL;
    const unsigned short* Bl = vTl + (size_t)head * DKH * SL;
    f32x4 acc[4];
    gemm_core2<false>(P, nullptr, nullptr, SL, Bh, Bl, SL, SL, m0, 0, acc);

    const int tid = threadIdx.x, wave = tid >> 6, lane = tid & 63;
    const int quad = lane >> 4, l16 = lane & 15;
    const int n = head >> 4, h = head & 15;
#pragma unroll
    for (int j = 0; j < 4; j++) {
        const int d = j * 16 + l16;
#pragma unroll
        for (int rr = 0; rr < 4; rr++) {
            const int s = m0 + wave * 16 + quad * 4 + rr;
            const size_t idx = ((size_t)n * SL + s) * ED + h * DKH + d;
            unsigned short hh, ll;
            split2(acc[j][rr], hh, ll);
            Oh[idx] = hh;
            Ol[idx] = ll;
        }
    }
}

// ---- output projection: out[m][e] = oh @ wo + bo; both operands pre-split ----
__global__ __launch_bounds__(256)
void k_outproj(const unsigned short* __restrict__ Ah, const unsigned short* __restrict__ Al,
               const unsigned short* __restrict__ Wh, const unsigned short* __restrict__ Wl,
               const float* __restrict__ bias, float* __restrict__ out)
{
    const int m0 = blockIdx.x * 64;
    const int n0 = blockIdx.y * 64;
    f32x4 acc[4];
    gemm_core2<true>(nullptr, Ah, Al, ED, Wh, Wl, ED, ED, m0, n0, acc);

    const int tid = threadIdx.x, wave = tid >> 6, lane = tid & 63;
    const int quad = lane >> 4, l16 = lane & 15;
#pragma unroll
    for (int j = 0; j < 4; j++) {
        const int col = n0 + j * 16 + l16;
        const float b = bias[col];
#pragma unroll
        for (int rr = 0; rr < 4; rr++) {
            const int m = m0 + wave * 16 + quad * 4 + rr;
            out[(size_t)m * ED + col] = acc[j][rr] + b;
        }
    }
}

extern "C" void kernel_launch(void* const* d_in, const int* in_sizes, int n_in,
                              void* d_out, int out_size, void* d_ws, size_t ws_size,
                              hipStream_t stream) {
    const float* q    = (const float*)d_in[0];
    const float* k    = (const float*)d_in[1];
    const float* v    = (const float*)d_in[2];
    const int*   mask = (const int*)d_in[3];
    const float* wq = (const float*)d_in[4];
    const float* bq = (const float*)d_in[5];
    const float* wk = (const float*)d_in[6];
    const float* bk = (const float*)d_in[7];
    const float* wv = (const float*)d_in[8];
    const float* bv = (const float*)d_in[9];
    const float* wo = (const float*)d_in[10];
    const float* bo = (const float*)d_in[11];

    float* out  = (float*)d_out;
    float* attn = out + (size_t)NB * SL * ED;   // second output: (N,H,S,S)

    // ---- workspace map (ushort planes), total 117.4 MB (< 134.2 MB used previously) ----
    unsigned short* w = (unsigned short*)d_ws;
    const size_t WPL = (size_t)ED * ED;             // 1,048,576 elems / weight plane
    unsigned short* wqT_h = w + 0 * WPL;
    unsigned short* wqT_l = w + 1 * WPL;
    unsigned short* wkT_h = w + 2 * WPL;
    unsigned short* wkT_l = w + 3 * WPL;
    unsigned short* wvT_h = w + 4 * WPL;
    unsigned short* wvT_l = w + 5 * WPL;
    unsigned short* woT_h = w + 6 * WPL;
    unsigned short* woT_l = w + 7 * WPL;
    unsigned short* base  = w + 8 * WPL;
    const size_t HPL = (size_t)NB * NH * SL * DKH;  // 8,388,608 elems / plane
    unsigned short* qh_h = base + 0 * HPL;
    unsigned short* qh_l = base + 1 * HPL;
    unsigned short* kh_h = base + 2 * HPL;
    unsigned short* kh_l = base + 3 * HPL;
    unsigned short* vT_h = base + 4 * HPL;
    unsigned short* vT_l = base + 5 * HPL;
    unsigned short* oh_h = qh_h;   // reuse: qh dead after k_logits, oh written by k_pv
    unsigned short* oh_l = qh_l;

    const dim3 blk(256);
    const dim3 gw(ED / 64, ED / 64);
    hipLaunchKernelGGL(k_wsplitT, gw, blk, 0, stream, wq, wqT_h, wqT_l);
    hipLaunchKernelGGL(k_wsplitT, gw, blk, 0, stream, wk, wkT_h, wkT_l);
    hipLaunchKernelGGL(k_wsplitT, gw, blk, 0, stream, wv, wvT_h, wvT_l);
    hipLaunchKernelGGL(k_wsplitT, gw, blk, 0, stream, wo, woT_h, woT_l);

    const dim3 gproj(8192 / 64, ED / 64);
    hipLaunchKernelGGL(k_projQK, gproj, blk, 0, stream, q, wqT_h, wqT_l, bq, qh_h, qh_l);
    hipLaunchKernelGGL(k_projQK, gproj, blk, 0, stream, k, wkT_h, wkT_l, bk, kh_h, kh_l);
    hipLaunchKernelGGL(k_projV,  gproj, blk, 0, stream, v, wvT_h, wvT_l, bv, vT_h, vT_l);

    const dim3 glog(SL / 64, SL / 64, NB * NH);
    hipLaunchKernelGGL(k_logits, glog, blk, 0, stream, qh_h, qh_l, kh_h, kh_l, mask, attn);

    hipLaunchKernelGGL(k_softmax, dim3(NB * NH * SL / 4), blk, 0, stream, attn);

    hipLaunchKernelGGL(k_pv, dim3(SL / 64, 1, NB * NH), blk, 0, stream, attn, vT_h, vT_l, oh_h, oh_l);

    hipLaunchKernelGGL(k_outproj, gproj, blk, 0, stream, oh_h, oh_l, woT_h, woT_l, bo, out);
}